// Round 2
// baseline (301.265 us; speedup 1.0000x reference)
//
#include <hip/hip_runtime.h>
#include <hip/hip_cooperative_groups.h>
#include <math.h>

namespace cg = cooperative_groups;

#define NB 8
#define NH 512
#define NW 512
#define ANG512 0.01227184630308513f
#define SPEC_D 16384   // per-depth stride of spec_wr/spec_wi (16*16*8*8)

// ---------------------------------------------------------------------------
// Phase A: row DFT, one row per WAVE (no block syncs).
// wave wid = b*512+row; lane l handles pixels w = l + 64j (j=0..3) paired
// with w+256 via the parity trick tw(k,w+256) = (-1)^k tw(k,w).
// Result: R[wid][0..7]=Re, [8..15]=Im.
// ---------------------------------------------------------------------------
__device__ __forceinline__ void phaseA(const float* __restrict__ x,
                                       float* __restrict__ R) {
    const int wid = (blockIdx.x << 2) + (threadIdx.x >> 6);  // 0..4095
    const int lane = threadIdx.x & 63;
    const int b = wid >> 9, row = wid & 511;
    const float* xr = x + ((size_t)(b * NH + row)) * NW;

    float p[16];
    #pragma unroll
    for (int j = 0; j < 16; ++j) p[j] = 0.f;

    #pragma unroll
    for (int j = 0; j < 4; ++j) {
        const int w = lane + (j << 6);
        const float xa = xr[w], xb = xr[w + 256];
        const float a = xa + xb, d = xa - xb;
        float c1, s1;
        __sincosf(ANG512 * (float)w, &s1, &c1);
        p[0] += a;
        p[1] = fmaf(d, c1, p[1]);
        p[9] = fmaf(-d, s1, p[9]);
        const float c2k = 2.f * c1;
        float ckm = 1.f, skm = 0.f, ck = c1, sk = s1;
        #pragma unroll
        for (int k = 2; k < 8; ++k) {
            const float cn = fmaf(c2k, ck, -ckm);
            const float sn = fmaf(c2k, sk, -skm);
            ckm = ck; skm = sk; ck = cn; sk = sn;
            const float v = (k & 1) ? d : a;
            p[k]     = fmaf(v, ck, p[k]);
            p[8 + k] = fmaf(-v, sk, p[8 + k]);
        }
    }
    // wave butterfly reduce of 16 accumulators
    #pragma unroll
    for (int m = 1; m < 64; m <<= 1) {
        #pragma unroll
        for (int j = 0; j < 16; ++j) p[j] += __shfl_xor(p[j], m);
    }
    if (lane < 16) R[((size_t)wid) * 16 + lane] = p[lane];
}

// ---------------------------------------------------------------------------
// Phase B: one block per (b,kx), bid < 64. Col-DFT of R -> X2; fc0 fold;
// 3-layer mode recurrence with spectral weights read DIRECTLY from global
// (each weight used exactly once -> LDS staging removed); fold fc1 -> AH.
// bid==0 additionally computes gvec/Kvec.
// sm: >= 2448 floats. Layout below.
// ---------------------------------------------------------------------------
__device__ __forceinline__ void phaseB(
        const float* __restrict__ R,
        const float* __restrict__ spec_wr, const float* __restrict__ spec_wi,
        const float* __restrict__ conv_w, const float* __restrict__ conv_b,
        const float* __restrict__ fc0_w, const float* __restrict__ fc0_b,
        const float* __restrict__ fc1_w, const float* __restrict__ fc1_b,
        float* __restrict__ AH, float* __restrict__ gvec, float* __restrict__ Kvec,
        float* sm, int bid) {
    float* partial = sm;          // 64   [4][16]
    float* X2      = sm + 64;     // 16
    float* Xr      = sm + 80;     // 128  [16][8]
    float* Xi      = sm + 208;    // 128
    float* Fr      = sm + 336;    // 128
    float* Fi      = sm + 464;    // 128
    float* Ar      = sm + 592;    // 128
    float* Ai      = sm + 720;    // 128
    float* Pm      = sm + 848;    // 512  [2][256]
    float* fc1_s   = sm + 1360;   // 1024
    float* ps      = sm + 2384;   // 64   (total 2448)

    const int tid = threadIdx.x;
    const int bb = bid >> 3;
    const int kx = bid & 7;

    // ---- Pm[0] = C2*C1, Pm[1] = C2, stage fc1 ----
    {
        const int o = tid >> 4, c = tid & 15;
        float s = 0.f;
        for (int k = 0; k < 16; ++k)
            s += conv_w[512 + o * 16 + k] * conv_w[256 + k * 16 + c];
        Pm[tid] = s;
    }
    Pm[256 + tid] = conv_w[512 + tid];
    #pragma unroll
    for (int k = 0; k < 4; ++k) fc1_s[tid + k * 256] = fc1_w[tid + k * 256];

    // ---- col-DFT: X2[ky] = sum_row R[bb,row,ky] e^{-2pi i kx row/512} ----
    float p[16];
    #pragma unroll
    for (int j = 0; j < 16; ++j) p[j] = 0.f;
    #pragma unroll
    for (int r2 = 0; r2 < 2; ++r2) {
        const int row = tid + r2 * 256;
        const float4* rp4 = (const float4*)(R + ((size_t)(bb * NH + row)) * 16);
        const float4 q0 = rp4[0], q1 = rp4[1], q2 = rp4[2], q3 = rp4[3];
        const float re[8] = {q0.x, q0.y, q0.z, q0.w, q1.x, q1.y, q1.z, q1.w};
        const float im[8] = {q2.x, q2.y, q2.z, q2.w, q3.x, q3.y, q3.z, q3.w};
        const int m = (kx * row) & 511;
        float cm, sm2;
        __sincosf(ANG512 * (float)m, &sm2, &cm);   // e^{-i th m} = (cm, -sm)
        #pragma unroll
        for (int k = 0; k < 8; ++k) {
            p[k]     += re[k] * cm + im[k] * sm2;
            p[8 + k] += im[k] * cm - re[k] * sm2;
        }
    }
    // wave butterfly + cross-wave sum (replaces 34.8 KB tb transpose-reduce)
    #pragma unroll
    for (int m = 1; m < 64; m <<= 1) {
        #pragma unroll
        for (int j = 0; j < 16; ++j) p[j] += __shfl_xor(p[j], m);
    }
    if ((tid & 63) < 16) partial[(tid >> 6) * 16 + (tid & 63)] = p[tid & 63];
    __syncthreads();
    if (tid < 16)
        X2[tid] = partial[tid] + partial[16 + tid] + partial[32 + tid] + partial[48 + tid];
    __syncthreads();

    // ---- recurrence: thread = (o,ky), tid < 128 ----
    const bool act = (tid < 128);
    const int o = tid >> 3, ky = tid & 7;
    if (act) {
        const float inv = 1.f / (512.f * 512.f);
        float xr0 = fc0_w[o] * X2[ky] * inv;
        float xi0 = fc0_w[o] * X2[8 + ky] * inv;
        if (kx == 0 && ky == 0) xr0 += fc0_b[o];
        Xr[o * 8 + ky] = xr0; Xi[o * 8 + ky] = xi0;
        Ar[o * 8 + ky] = 0.f; Ai[o * 8 + ky] = 0.f;
    }
    __syncthreads();

    for (int dd = 0; dd < 3; ++dd) {
        if (act) {
            float fr = 0.f, fi = 0.f;
            const float* wrp = spec_wr + (size_t)dd * SPEC_D + o * 64 + kx * 8 + ky;
            const float* wip = spec_wi + (size_t)dd * SPEC_D + o * 64 + kx * 8 + ky;
            #pragma unroll
            for (int i = 0; i < 16; ++i) {
                const float wre = wrp[i * 1024];
                const float wim = wip[i * 1024];
                const float xr0 = Xr[i * 8 + ky], xi0 = Xi[i * 8 + ky];
                fr += xr0 * wre - xi0 * wim;
                fi += xr0 * wim + xi0 * wre;
            }
            Fr[o * 8 + ky] = fr; Fi[o * 8 + ky] = fi;
        }
        __syncthreads();
        float xnr = 0.f, xni = 0.f;
        if (act) {
            float ar, ai;
            if (dd == 2) {
                ar = Fr[o * 8 + ky]; ai = Fi[o * 8 + ky];
            } else {
                ar = 0.f; ai = 0.f;
                #pragma unroll
                for (int c = 0; c < 16; ++c) {
                    const float pv = Pm[dd * 256 + o * 16 + c];
                    ar = fmaf(pv, Fr[c * 8 + ky], ar);
                    ai = fmaf(pv, Fi[c * 8 + ky], ai);
                }
            }
            Ar[o * 8 + ky] += ar; Ai[o * 8 + ky] += ai;
            if (dd < 2) {
                const float fr0 = Fr[o * 8 + ky], fi0 = Fi[o * 8 + ky];
                if (ky == 0) {
                    if (kx == 0) { xnr = fr0; xni = 0.f; }
                    else         { xnr = 0.5f * fr0; xni = 0.5f * fi0; }
                } else { xnr = fr0; xni = fi0; }
                #pragma unroll
                for (int c = 0; c < 16; ++c) {
                    const float cc = conv_w[dd * 256 + o * 16 + c];
                    xnr = fmaf(cc, Xr[c * 8 + ky], xnr);
                    xni = fmaf(cc, Xi[c * 8 + ky], xni);
                }
                if (kx == 0 && ky == 0) xnr += conv_b[dd * 16 + o];
            }
        }
        __syncthreads();
        if (act && dd < 2) { Xr[o * 8 + ky] = xnr; Xi[o * 8 + ky] = xni; }
        __syncthreads();
    }

    // ---- fold fc1 -> AH[b,hd,ky,kx] (interleaved complex) ----
    #pragma unroll
    for (int k2 = 0; k2 < 2; ++k2) {
        const int idx = tid + k2 * 256;      // hd*8 + ky2
        const int hd = idx >> 3, ky2 = idx & 7;
        float ar = 0.f, ai = 0.f;
        #pragma unroll
        for (int c = 0; c < 16; ++c) {
            const float f = fc1_s[c * 64 + hd];
            ar = fmaf(f, Ar[c * 8 + ky2], ar);
            ai = fmaf(f, Ai[c * 8 + ky2], ai);
        }
        const float ck = (ky2 == 0) ? 1.f : 2.f;    // Hermitian doubling
        const size_t off = ((((size_t)(bb * 64 + hd)) * 8 + ky2) * 8 + kx) * 2;
        AH[off] = ck * ar;
        AH[off + 1] = ck * ai;
    }

    // ---- bid 0: gvec = fc1^T(P0*C0*fc0_w); Kvec = fc1_b + fc1^T(evec) ----
    if (bid == 0) {
        if (tid < 16) {
            float su = 0.f, sb = 0.f;
            for (int c = 0; c < 16; ++c) {
                su += conv_w[tid * 16 + c] * fc0_w[c];
                sb += conv_w[tid * 16 + c] * fc0_b[c];
            }
            ps[tid] = su; ps[16 + tid] = sb;
        }
        __syncthreads();
        if (tid < 16) {
            float dv = 0.f, ev = conv_b[32 + tid];
            for (int k = 0; k < 16; ++k) {
                dv += Pm[tid * 16 + k] * ps[k];
                ev += Pm[tid * 16 + k] * (ps[16 + k] + conv_b[k]);
                ev += conv_w[512 + tid * 16 + k] * conv_b[16 + k];
            }
            ps[32 + tid] = dv; ps[48 + tid] = ev;
        }
        __syncthreads();
        if (tid < 64) {
            float g = 0.f, K = fc1_b[tid];
            for (int c = 0; c < 16; ++c) {
                g = fmaf(fc1_w[c * 64 + tid], ps[32 + c], g);
                K = fmaf(fc1_w[c * 64 + tid], ps[48 + c], K);
            }
            gvec[tid] = g; Kvec[tid] = K;
        }
    }
}

// ---------------------------------------------------------------------------
// Phase C: k_head body. 4 rows/block (wave = row), 8 px/thread.
// sm: 4096 floats; WHr = sm[0..2047] as [4][512], WHi = sm[2048..4095].
// ---------------------------------------------------------------------------
__device__ __forceinline__ void phaseC(
        const float* __restrict__ x, const float* __restrict__ AH,
        const float* __restrict__ gvec, const float* __restrict__ Kvec,
        const float* __restrict__ fc2_w, const float* __restrict__ fc2_b,
        float* __restrict__ out, float* sm) {
    float* WHr = sm;
    float* WHi = sm + 2048;

    const int tid = threadIdx.x;
    const int b = blockIdx.x >> 7;       // 1024 blocks total
    const int rp = blockIdx.x & 127;     // group of 4 rows
    const int rl = tid >> 6;             // wave index = local row
    const int row = rp * 4 + rl;
    const int w0 = tid & 63;

    // hoist x loads (coalesced, latency overlapped with WH build)
    const float* xp = x + ((size_t)(b * NH + row)) * NW + w0;
    float xv[8];
    #pragma unroll
    for (int j = 0; j < 8; ++j) xv[j] = xp[j * 64];

    // ---- WH build: 8 entries/thread for this wave's row ----
    {
        float c1, s1;
        __sincosf(ANG512 * (float)row, &s1, &c1);
        float ctr[8], str[8];
        ctr[0] = 1.f; str[0] = 0.f; ctr[1] = c1; str[1] = s1;
        const float c2k = 2.f * c1;
        #pragma unroll
        for (int k = 2; k < 8; ++k) {
            ctr[k] = fmaf(c2k, ctr[k - 1], -ctr[k - 2]);
            str[k] = fmaf(c2k, str[k - 1], -str[k - 2]);
        }
        #pragma unroll
        for (int j = 0; j < 8; ++j) {
            const int idx = w0 + j * 64;     // hd*8 + ky
            const int hd = idx >> 3, ky = idx & 7;
            const float4* ap = (const float4*)(AH + ((size_t)(b * 64 + hd) * 8 + ky) * 16);
            const float4 a0 = ap[0], a1 = ap[1], a2 = ap[2], a3 = ap[3];
            float wr = a0.x, wi = a0.y;      // kx=0
            wr = fmaf(a0.z, ctr[1], wr); wr = fmaf(-a0.w, str[1], wr);
            wi = fmaf(a0.z, str[1], wi); wi = fmaf(a0.w, ctr[1], wi);
            wr = fmaf(a1.x, ctr[2], wr); wr = fmaf(-a1.y, str[2], wr);
            wi = fmaf(a1.x, str[2], wi); wi = fmaf(a1.y, ctr[2], wi);
            wr = fmaf(a1.z, ctr[3], wr); wr = fmaf(-a1.w, str[3], wr);
            wi = fmaf(a1.z, str[3], wi); wi = fmaf(a1.w, ctr[3], wi);
            wr = fmaf(a2.x, ctr[4], wr); wr = fmaf(-a2.y, str[4], wr);
            wi = fmaf(a2.x, str[4], wi); wi = fmaf(a2.y, ctr[4], wi);
            wr = fmaf(a2.z, ctr[5], wr); wr = fmaf(-a2.w, str[5], wr);
            wi = fmaf(a2.z, str[5], wi); wi = fmaf(a2.w, ctr[5], wi);
            wr = fmaf(a3.x, ctr[6], wr); wr = fmaf(-a3.y, str[6], wr);
            wi = fmaf(a3.x, str[6], wi); wi = fmaf(a3.y, ctr[6], wi);
            wr = fmaf(a3.z, ctr[7], wr); wr = fmaf(-a3.w, str[7], wr);
            wi = fmaf(a3.z, str[7], wi); wi = fmaf(a3.w, ctr[7], wi);
            if (ky == 0) wr += Kvec[hd];
            WHr[rl * 512 + idx] = wr;
            WHi[rl * 512 + idx] = wi;
        }
    }
    __syncthreads();

    // ---- 8 px/thread: w0 + 64*j ----
    {
        float c1, s1;
        __sincosf(ANG512 * (float)w0, &s1, &c1);
        float ct[8], st[8];
        ct[0] = 1.f; st[0] = 0.f; ct[1] = c1; st[1] = s1;
        const float c2k = 2.f * c1;
        #pragma unroll
        for (int k = 2; k < 8; ++k) {
            ct[k] = fmaf(c2k, ct[k - 1], -ct[k - 2]);
            st[k] = fmaf(c2k, st[k - 1], -st[k - 2]);
        }
        const float r2c = 0.70710678118654752f;
        const float* WR = WHr + rl * 512;
        const float* WI = WHi + rl * 512;
        const float fc2b = fc2_b[0];
        float acc[8];
        #pragma unroll
        for (int j = 0; j < 8; ++j) acc[j] = fc2b;

        #pragma unroll 4
        for (int hd = 0; hd < 64; ++hd) {
            const float4* r4 = (const float4*)(WR + hd * 8);
            const float4 wa = r4[0], wb = r4[1];
            const float4* i4 = (const float4*)(WI + hd * 8);
            const float4 va = i4[0], vb = i4[1];
            const float tr0 = wa.x;
            const float tr1 = wa.y * ct[1] - va.y * st[1];
            const float ti1 = wa.y * st[1] + va.y * ct[1];
            const float tr2 = wa.z * ct[2] - va.z * st[2];
            const float ti2 = wa.z * st[2] + va.z * ct[2];
            const float tr3 = wa.w * ct[3] - va.w * st[3];
            const float ti3 = wa.w * st[3] + va.w * ct[3];
            const float tr4 = wb.x * ct[4] - vb.x * st[4];
            const float tr5 = wb.y * ct[5] - vb.y * st[5];
            const float ti5 = wb.y * st[5] + vb.y * ct[5];
            const float tr6 = wb.z * ct[6] - vb.z * st[6];
            const float ti6 = wb.z * st[6] + vb.z * ct[6];
            const float tr7 = wb.w * ct[7] - vb.w * st[7];
            const float ti7 = wb.w * st[7] + vb.w * ct[7];

            const float gh = gvec[hd];
            const float w2 = fc2_w[hd];

            // quad 1: pixels w0 + 128m  (i^ky rotation)
            const float A0 = tr0 + tr4, A2 = tr2 + tr6;
            const float E = A0 + A2, D = A0 - A2;
            const float B13 = (tr1 + tr5) + (tr3 + tr7);
            const float U = (ti1 + ti5) - (ti3 + ti7);
            const float s0 = fmaf(gh, xv[0], E + B13);
            const float s2 = fmaf(gh, xv[2], D - U);
            const float s4 = fmaf(gh, xv[4], E - B13);
            const float s6 = fmaf(gh, xv[6], D + U);
            acc[0] = fmaf(fmaxf(s0, 0.f), w2, acc[0]);
            acc[2] = fmaf(fmaxf(s2, 0.f), w2, acc[2]);
            acc[4] = fmaf(fmaxf(s4, 0.f), w2, acc[4]);
            acc[6] = fmaf(fmaxf(s6, 0.f), w2, acc[6]);

            // quad 2: pixels w0+64+128m  (extra e^{i ky pi/4} rotation)
            const float P = tr0 - tr4, Q = ti6 - ti2;
            const float E2 = P + Q, D2 = P - Q;
            const float B2 = r2c * (((tr1 - ti1) - (tr5 - ti5)) + ((tr7 + ti7) - (tr3 + ti3)));
            const float U2 = r2c * (((tr1 + ti1) - (tr5 + ti5)) - ((tr3 - ti3) + (ti7 - tr7)));
            const float s1p = fmaf(gh, xv[1], E2 + B2);
            const float s3p = fmaf(gh, xv[3], D2 - U2);
            const float s5p = fmaf(gh, xv[5], E2 - B2);
            const float s7p = fmaf(gh, xv[7], D2 + U2);
            acc[1] = fmaf(fmaxf(s1p, 0.f), w2, acc[1]);
            acc[3] = fmaf(fmaxf(s3p, 0.f), w2, acc[3]);
            acc[5] = fmaf(fmaxf(s5p, 0.f), w2, acc[5]);
            acc[7] = fmaf(fmaxf(s7p, 0.f), w2, acc[7]);
        }
        float* op = out + ((size_t)(b * NH + row)) * NW + w0;
        #pragma unroll
        for (int j = 0; j < 8; ++j) op[j * 64] = acc[j];
    }
}

// ---------------------------------------------------------------------------
// Fused cooperative kernel: 1024 blocks x 256 threads, 4 blocks/CU
// co-resident (16 KB LDS, VGPR<=128). 2 grid syncs replace 3 launch gaps.
// ---------------------------------------------------------------------------
__global__ __launch_bounds__(256, 4) void k_fused(
        const float* __restrict__ x,
        const float* __restrict__ spec_wr, const float* __restrict__ spec_wi,
        const float* __restrict__ conv_w, const float* __restrict__ conv_b,
        const float* __restrict__ fc0_w, const float* __restrict__ fc0_b,
        const float* __restrict__ fc1_w, const float* __restrict__ fc1_b,
        const float* __restrict__ fc2_w, const float* __restrict__ fc2_b,
        float* __restrict__ R, float* __restrict__ AH,
        float* __restrict__ gvec, float* __restrict__ Kvec,
        float* __restrict__ out) {
    __shared__ __align__(16) float sm[4096];

    phaseA(x, R);
    cg::this_grid().sync();
    if (blockIdx.x < 64)
        phaseB(R, spec_wr, spec_wi, conv_w, conv_b, fc0_w, fc0_b,
               fc1_w, fc1_b, AH, gvec, Kvec, sm, blockIdx.x);
    cg::this_grid().sync();
    phaseC(x, AH, gvec, Kvec, fc2_w, fc2_b, out, sm);
}

// ---------------------------------------------------------------------------
// Fallback (non-cooperative) wrappers, used only if cooperative launch fails.
// ---------------------------------------------------------------------------
__global__ __launch_bounds__(256, 4) void k_pA(const float* __restrict__ x,
                                               float* __restrict__ R) {
    phaseA(x, R);
}

__global__ __launch_bounds__(256) void k_pB(
        const float* __restrict__ R,
        const float* __restrict__ spec_wr, const float* __restrict__ spec_wi,
        const float* __restrict__ conv_w, const float* __restrict__ conv_b,
        const float* __restrict__ fc0_w, const float* __restrict__ fc0_b,
        const float* __restrict__ fc1_w, const float* __restrict__ fc1_b,
        float* __restrict__ AH, float* __restrict__ gvec, float* __restrict__ Kvec) {
    __shared__ __align__(16) float sm[2448];
    phaseB(R, spec_wr, spec_wi, conv_w, conv_b, fc0_w, fc0_b,
           fc1_w, fc1_b, AH, gvec, Kvec, sm, blockIdx.x);
}

__global__ __launch_bounds__(256, 4) void k_pC(
        const float* __restrict__ x, const float* __restrict__ AH,
        const float* __restrict__ gvec, const float* __restrict__ Kvec,
        const float* __restrict__ fc2_w, const float* __restrict__ fc2_b,
        float* __restrict__ out) {
    __shared__ __align__(16) float sm[4096];
    phaseC(x, AH, gvec, Kvec, fc2_w, fc2_b, out, sm);
}

// ---------------------------------------------------------------------------
extern "C" void kernel_launch(void* const* d_in, const int* in_sizes, int n_in,
                              void* d_out, int out_size, void* d_ws, size_t ws_size,
                              hipStream_t stream) {
    const float* x       = (const float*)d_in[0];
    const float* fc0_w   = (const float*)d_in[1];
    const float* fc0_b   = (const float*)d_in[2];
    const float* spec_wr = (const float*)d_in[3];
    const float* spec_wi = (const float*)d_in[4];
    const float* conv_w  = (const float*)d_in[5];
    const float* conv_b  = (const float*)d_in[6];
    const float* fc1_w   = (const float*)d_in[7];
    const float* fc1_b   = (const float*)d_in[8];
    const float* fc2_w   = (const float*)d_in[9];
    const float* fc2_b   = (const float*)d_in[10];
    float* outp = (float*)d_out;

    char* ws = (char*)d_ws;
    float* R  = (float*)ws;                       // 8*512*16 floats = 256 KB
    float* AH = (float*)(ws + 262144);            // 8*64*64*2 floats = 256 KB
    float* gv = (float*)(ws + 524288);            // 64 floats
    float* Kv = (float*)(ws + 524288 + 256);      // 64 floats

    void* args[] = {(void*)&x, (void*)&spec_wr, (void*)&spec_wi,
                    (void*)&conv_w, (void*)&conv_b, (void*)&fc0_w, (void*)&fc0_b,
                    (void*)&fc1_w, (void*)&fc1_b, (void*)&fc2_w, (void*)&fc2_b,
                    (void*)&R, (void*)&AH, (void*)&gv, (void*)&Kv, (void*)&outp};
    hipError_t err = hipLaunchCooperativeKernel((const void*)k_fused,
                                                dim3(1024), dim3(256),
                                                args, 0, stream);
    if (err != hipSuccess) {
        (void)hipGetLastError();   // clear sticky error, use 3-kernel fallback
        k_pA<<<1024, 256, 0, stream>>>(x, R);
        k_pB<<<64, 256, 0, stream>>>(R, spec_wr, spec_wi, conv_w, conv_b,
                                     fc0_w, fc0_b, fc1_w, fc1_b, AH, gv, Kv);
        k_pC<<<1024, 256, 0, stream>>>(x, AH, gv, Kv, fc2_w, fc2_b, outp);
    }
}

// Round 3
// 149.864 us; speedup vs baseline: 2.0103x; 2.0103x over previous
//
#include <hip/hip_runtime.h>
#include <math.h>

#define NB 8
#define NH 512
#define NW 512
#define ANG512 0.01227184630308513f
#define SPEC_D 16384   // per-depth stride of spec_wr/spec_wi (16*16*8*8)

#define DEV_SCOPE __HIP_MEMORY_SCOPE_AGENT

// ---------------------------------------------------------------------------
// k1: row DFT, one row per WAVE (no block syncs, no LDS).
// wave wid = b*512+row; lane l handles pixels w = l + 64j (j=0..3) paired
// with w+256 via the parity trick tw(k,w+256) = (-1)^k tw(k,w).
// Result: R[wid][0..7]=Re, [8..15]=Im.  Block 0 also resets the AH flag
// (device-coherent store) -- guarantees flag==0 before k2 of SAME replay.
// ---------------------------------------------------------------------------
__global__ __launch_bounds__(256) void k_rowdft(const float* __restrict__ x,
                                                float* __restrict__ R,
                                                int* __restrict__ flag) {
    if (blockIdx.x == 0 && threadIdx.x == 0)
        __hip_atomic_store(flag, 0, __ATOMIC_RELAXED, DEV_SCOPE);

    const int wid = (blockIdx.x << 2) + (threadIdx.x >> 6);  // 0..4095
    const int lane = threadIdx.x & 63;
    const int b = wid >> 9, row = wid & 511;
    const float* xr = x + ((size_t)(b * NH + row)) * NW;

    float p[16];
    #pragma unroll
    for (int j = 0; j < 16; ++j) p[j] = 0.f;

    #pragma unroll
    for (int j = 0; j < 4; ++j) {
        const int w = lane + (j << 6);
        const float xa = xr[w], xb = xr[w + 256];
        const float a = xa + xb, d = xa - xb;
        float c1, s1;
        __sincosf(ANG512 * (float)w, &s1, &c1);
        p[0] += a;
        p[1] = fmaf(d, c1, p[1]);
        p[9] = fmaf(-d, s1, p[9]);
        const float c2k = 2.f * c1;
        float ckm = 1.f, skm = 0.f, ck = c1, sk = s1;
        #pragma unroll
        for (int k = 2; k < 8; ++k) {
            const float cn = fmaf(c2k, ck, -ckm);
            const float sn = fmaf(c2k, sk, -skm);
            ckm = ck; skm = sk; ck = cn; sk = sn;
            const float v = (k & 1) ? d : a;
            p[k]     = fmaf(v, ck, p[k]);
            p[8 + k] = fmaf(-v, sk, p[8 + k]);
        }
    }
    // wave butterfly reduce of 16 accumulators
    #pragma unroll
    for (int m = 1; m < 64; m <<= 1) {
        #pragma unroll
        for (int j = 0; j < 16; ++j) p[j] += __shfl_xor(p[j], m);
    }
    if (lane < 16) R[((size_t)wid) * 16 + lane] = p[lane];
}

// ---------------------------------------------------------------------------
// Phase B (device fn): one block per (b,kx), bid < 64. Col-DFT of R -> X2;
// fc0 fold; 3-layer mode recurrence with spectral weights read directly from
// global (single-use -> no LDS staging); fold fc1 -> AH.
// AH/gvec/Kvec written with DEVICE-SCOPE stores (bypass local L2) so the
// post-flag readers in other blocks see fresh values via plain loads.
// sm: >= 2448 floats.
// ---------------------------------------------------------------------------
__device__ __forceinline__ void phaseB(
        const float* __restrict__ R,
        const float* __restrict__ spec_wr, const float* __restrict__ spec_wi,
        const float* __restrict__ conv_w, const float* __restrict__ conv_b,
        const float* __restrict__ fc0_w, const float* __restrict__ fc0_b,
        const float* __restrict__ fc1_w, const float* __restrict__ fc1_b,
        float* __restrict__ AH, float* __restrict__ gvec, float* __restrict__ Kvec,
        float* sm, int bid) {
    float* partial = sm;          // 64   [4][16]
    float* X2      = sm + 64;     // 16
    float* Xr      = sm + 80;     // 128  [16][8]
    float* Xi      = sm + 208;    // 128
    float* Fr      = sm + 336;    // 128
    float* Fi      = sm + 464;    // 128
    float* Ar      = sm + 592;    // 128
    float* Ai      = sm + 720;    // 128
    float* Pm      = sm + 848;    // 512  [2][256]
    float* fc1_s   = sm + 1360;   // 1024
    float* ps      = sm + 2384;   // 64   (total 2448)

    const int tid = threadIdx.x;
    const int bb = bid >> 3;
    const int kx = bid & 7;

    // ---- Pm[0] = C2*C1, Pm[1] = C2, stage fc1 ----
    {
        const int o = tid >> 4, c = tid & 15;
        float s = 0.f;
        for (int k = 0; k < 16; ++k)
            s += conv_w[512 + o * 16 + k] * conv_w[256 + k * 16 + c];
        Pm[tid] = s;
    }
    Pm[256 + tid] = conv_w[512 + tid];
    #pragma unroll
    for (int k = 0; k < 4; ++k) fc1_s[tid + k * 256] = fc1_w[tid + k * 256];

    // ---- col-DFT: X2[ky] = sum_row R[bb,row,ky] e^{-2pi i kx row/512} ----
    float p[16];
    #pragma unroll
    for (int j = 0; j < 16; ++j) p[j] = 0.f;
    #pragma unroll
    for (int r2 = 0; r2 < 2; ++r2) {
        const int row = tid + r2 * 256;
        const float4* rp4 = (const float4*)(R + ((size_t)(bb * NH + row)) * 16);
        const float4 q0 = rp4[0], q1 = rp4[1], q2 = rp4[2], q3 = rp4[3];
        const float re[8] = {q0.x, q0.y, q0.z, q0.w, q1.x, q1.y, q1.z, q1.w};
        const float im[8] = {q2.x, q2.y, q2.z, q2.w, q3.x, q3.y, q3.z, q3.w};
        const int m = (kx * row) & 511;
        float cm, sm2;
        __sincosf(ANG512 * (float)m, &sm2, &cm);   // e^{-i th m} = (cm, -sm)
        #pragma unroll
        for (int k = 0; k < 8; ++k) {
            p[k]     += re[k] * cm + im[k] * sm2;
            p[8 + k] += im[k] * cm - re[k] * sm2;
        }
    }
    // wave butterfly + cross-wave sum
    #pragma unroll
    for (int m = 1; m < 64; m <<= 1) {
        #pragma unroll
        for (int j = 0; j < 16; ++j) p[j] += __shfl_xor(p[j], m);
    }
    if ((tid & 63) < 16) partial[(tid >> 6) * 16 + (tid & 63)] = p[tid & 63];
    __syncthreads();
    if (tid < 16)
        X2[tid] = partial[tid] + partial[16 + tid] + partial[32 + tid] + partial[48 + tid];
    __syncthreads();

    // ---- recurrence: thread = (o,ky), tid < 128 ----
    const bool act = (tid < 128);
    const int o = tid >> 3, ky = tid & 7;
    if (act) {
        const float inv = 1.f / (512.f * 512.f);
        float xr0 = fc0_w[o] * X2[ky] * inv;
        float xi0 = fc0_w[o] * X2[8 + ky] * inv;
        if (kx == 0 && ky == 0) xr0 += fc0_b[o];
        Xr[o * 8 + ky] = xr0; Xi[o * 8 + ky] = xi0;
        Ar[o * 8 + ky] = 0.f; Ai[o * 8 + ky] = 0.f;
    }
    __syncthreads();

    for (int dd = 0; dd < 3; ++dd) {
        if (act) {
            float fr = 0.f, fi = 0.f;
            const float* wrp = spec_wr + (size_t)dd * SPEC_D + o * 64 + kx * 8 + ky;
            const float* wip = spec_wi + (size_t)dd * SPEC_D + o * 64 + kx * 8 + ky;
            #pragma unroll
            for (int i = 0; i < 16; ++i) {
                const float wre = wrp[i * 1024];
                const float wim = wip[i * 1024];
                const float xr0 = Xr[i * 8 + ky], xi0 = Xi[i * 8 + ky];
                fr += xr0 * wre - xi0 * wim;
                fi += xr0 * wim + xi0 * wre;
            }
            Fr[o * 8 + ky] = fr; Fi[o * 8 + ky] = fi;
        }
        __syncthreads();
        float xnr = 0.f, xni = 0.f;
        if (act) {
            float ar, ai;
            if (dd == 2) {
                ar = Fr[o * 8 + ky]; ai = Fi[o * 8 + ky];
            } else {
                ar = 0.f; ai = 0.f;
                #pragma unroll
                for (int c = 0; c < 16; ++c) {
                    const float pv = Pm[dd * 256 + o * 16 + c];
                    ar = fmaf(pv, Fr[c * 8 + ky], ar);
                    ai = fmaf(pv, Fi[c * 8 + ky], ai);
                }
            }
            Ar[o * 8 + ky] += ar; Ai[o * 8 + ky] += ai;
            if (dd < 2) {
                const float fr0 = Fr[o * 8 + ky], fi0 = Fi[o * 8 + ky];
                if (ky == 0) {
                    if (kx == 0) { xnr = fr0; xni = 0.f; }
                    else         { xnr = 0.5f * fr0; xni = 0.5f * fi0; }
                } else { xnr = fr0; xni = fi0; }
                #pragma unroll
                for (int c = 0; c < 16; ++c) {
                    const float cc = conv_w[dd * 256 + o * 16 + c];
                    xnr = fmaf(cc, Xr[c * 8 + ky], xnr);
                    xni = fmaf(cc, Xi[c * 8 + ky], xni);
                }
                if (kx == 0 && ky == 0) xnr += conv_b[dd * 16 + o];
            }
        }
        __syncthreads();
        if (act && dd < 2) { Xr[o * 8 + ky] = xnr; Xi[o * 8 + ky] = xni; }
        __syncthreads();
    }

    // ---- fold fc1 -> AH[b,hd,ky,kx], device-coherent stores ----
    #pragma unroll
    for (int k2 = 0; k2 < 2; ++k2) {
        const int idx = tid + k2 * 256;      // hd*8 + ky2
        const int hd = idx >> 3, ky2 = idx & 7;
        float ar = 0.f, ai = 0.f;
        #pragma unroll
        for (int c = 0; c < 16; ++c) {
            const float f = fc1_s[c * 64 + hd];
            ar = fmaf(f, Ar[c * 8 + ky2], ar);
            ai = fmaf(f, Ai[c * 8 + ky2], ai);
        }
        const float ck = (ky2 == 0) ? 1.f : 2.f;    // Hermitian doubling
        const size_t off = ((((size_t)(bb * 64 + hd)) * 8 + ky2) * 8 + kx) * 2;
        __hip_atomic_store(&AH[off],     ck * ar, __ATOMIC_RELAXED, DEV_SCOPE);
        __hip_atomic_store(&AH[off + 1], ck * ai, __ATOMIC_RELAXED, DEV_SCOPE);
    }

    // ---- bid 0: gvec = fc1^T(P0*C0*fc0_w); Kvec = fc1_b + fc1^T(evec) ----
    if (bid == 0) {
        if (tid < 16) {
            float su = 0.f, sb = 0.f;
            for (int c = 0; c < 16; ++c) {
                su += conv_w[tid * 16 + c] * fc0_w[c];
                sb += conv_w[tid * 16 + c] * fc0_b[c];
            }
            ps[tid] = su; ps[16 + tid] = sb;
        }
        __syncthreads();
        if (tid < 16) {
            float dv = 0.f, ev = conv_b[32 + tid];
            for (int k = 0; k < 16; ++k) {
                dv += Pm[tid * 16 + k] * ps[k];
                ev += Pm[tid * 16 + k] * (ps[16 + k] + conv_b[k]);
                ev += conv_w[512 + tid * 16 + k] * conv_b[16 + k];
            }
            ps[32 + tid] = dv; ps[48 + tid] = ev;
        }
        __syncthreads();
        if (tid < 64) {
            float g = 0.f, K = fc1_b[tid];
            for (int c = 0; c < 16; ++c) {
                g = fmaf(fc1_w[c * 64 + tid], ps[32 + c], g);
                K = fmaf(fc1_w[c * 64 + tid], ps[48 + c], K);
            }
            __hip_atomic_store(&gvec[tid], g, __ATOMIC_RELAXED, DEV_SCOPE);
            __hip_atomic_store(&Kvec[tid], K, __ATOMIC_RELAXED, DEV_SCOPE);
        }
    }
}

// ---------------------------------------------------------------------------
// Phase C (device fn): head. 4 rows/block (wave = row), 8 px/thread.
// sm: 4096 floats; WHr = sm[0..2047] as [4][512], WHi = sm[2048..4095].
// ---------------------------------------------------------------------------
__device__ __forceinline__ void phaseC(
        const float* __restrict__ x, const float* __restrict__ AH,
        const float* __restrict__ gvec, const float* __restrict__ Kvec,
        const float* __restrict__ fc2_w, const float* __restrict__ fc2_b,
        float* __restrict__ out, float* sm) {
    float* WHr = sm;
    float* WHi = sm + 2048;

    const int tid = threadIdx.x;
    const int b = blockIdx.x >> 7;       // 1024 blocks total
    const int rp = blockIdx.x & 127;     // group of 4 rows
    const int rl = tid >> 6;             // wave index = local row
    const int row = rp * 4 + rl;
    const int w0 = tid & 63;

    const float* xp = x + ((size_t)(b * NH + row)) * NW + w0;
    float xv[8];
    #pragma unroll
    for (int j = 0; j < 8; ++j) xv[j] = xp[j * 64];

    // ---- WH build: 8 entries/thread for this wave's row ----
    {
        float c1, s1;
        __sincosf(ANG512 * (float)row, &s1, &c1);
        float ctr[8], str[8];
        ctr[0] = 1.f; str[0] = 0.f; ctr[1] = c1; str[1] = s1;
        const float c2k = 2.f * c1;
        #pragma unroll
        for (int k = 2; k < 8; ++k) {
            ctr[k] = fmaf(c2k, ctr[k - 1], -ctr[k - 2]);
            str[k] = fmaf(c2k, str[k - 1], -str[k - 2]);
        }
        #pragma unroll
        for (int j = 0; j < 8; ++j) {
            const int idx = w0 + j * 64;     // hd*8 + ky
            const int hd = idx >> 3, ky = idx & 7;
            const float4* ap = (const float4*)(AH + ((size_t)(b * 64 + hd) * 8 + ky) * 16);
            const float4 a0 = ap[0], a1 = ap[1], a2 = ap[2], a3 = ap[3];
            float wr = a0.x, wi = a0.y;      // kx=0
            wr = fmaf(a0.z, ctr[1], wr); wr = fmaf(-a0.w, str[1], wr);
            wi = fmaf(a0.z, str[1], wi); wi = fmaf(a0.w, ctr[1], wi);
            wr = fmaf(a1.x, ctr[2], wr); wr = fmaf(-a1.y, str[2], wr);
            wi = fmaf(a1.x, str[2], wi); wi = fmaf(a1.y, ctr[2], wi);
            wr = fmaf(a1.z, ctr[3], wr); wr = fmaf(-a1.w, str[3], wr);
            wi = fmaf(a1.z, str[3], wi); wi = fmaf(a1.w, ctr[3], wi);
            wr = fmaf(a2.x, ctr[4], wr); wr = fmaf(-a2.y, str[4], wr);
            wi = fmaf(a2.x, str[4], wi); wi = fmaf(a2.y, ctr[4], wi);
            wr = fmaf(a2.z, ctr[5], wr); wr = fmaf(-a2.w, str[5], wr);
            wi = fmaf(a2.z, str[5], wi); wi = fmaf(a2.w, ctr[5], wi);
            wr = fmaf(a3.x, ctr[6], wr); wr = fmaf(-a3.y, str[6], wr);
            wi = fmaf(a3.x, str[6], wi); wi = fmaf(a3.y, ctr[6], wi);
            wr = fmaf(a3.z, ctr[7], wr); wr = fmaf(-a3.w, str[7], wr);
            wi = fmaf(a3.w, ctr[7], wi); wi = fmaf(a3.z, str[7], wi);
            if (ky == 0) wr += Kvec[hd];
            WHr[rl * 512 + idx] = wr;
            WHi[rl * 512 + idx] = wi;
        }
    }
    __syncthreads();

    // ---- 8 px/thread: w0 + 64*j ----
    {
        float c1, s1;
        __sincosf(ANG512 * (float)w0, &s1, &c1);
        float ct[8], st[8];
        ct[0] = 1.f; st[0] = 0.f; ct[1] = c1; st[1] = s1;
        const float c2k = 2.f * c1;
        #pragma unroll
        for (int k = 2; k < 8; ++k) {
            ct[k] = fmaf(c2k, ct[k - 1], -ct[k - 2]);
            st[k] = fmaf(c2k, st[k - 1], -st[k - 2]);
        }
        const float r2c = 0.70710678118654752f;
        const float* WR = WHr + rl * 512;
        const float* WI = WHi + rl * 512;
        const float fc2b = fc2_b[0];
        float acc[8];
        #pragma unroll
        for (int j = 0; j < 8; ++j) acc[j] = fc2b;

        #pragma unroll 4
        for (int hd = 0; hd < 64; ++hd) {
            const float4* r4 = (const float4*)(WR + hd * 8);
            const float4 wa = r4[0], wb = r4[1];
            const float4* i4 = (const float4*)(WI + hd * 8);
            const float4 va = i4[0], vb = i4[1];
            const float tr0 = wa.x;
            const float tr1 = wa.y * ct[1] - va.y * st[1];
            const float ti1 = wa.y * st[1] + va.y * ct[1];
            const float tr2 = wa.z * ct[2] - va.z * st[2];
            const float ti2 = wa.z * st[2] + va.z * ct[2];
            const float tr3 = wa.w * ct[3] - va.w * st[3];
            const float ti3 = wa.w * st[3] + va.w * ct[3];
            const float tr4 = wb.x * ct[4] - vb.x * st[4];
            const float tr5 = wb.y * ct[5] - vb.y * st[5];
            const float ti5 = wb.y * st[5] + vb.y * ct[5];
            const float tr6 = wb.z * ct[6] - vb.z * st[6];
            const float ti6 = wb.z * st[6] + vb.z * ct[6];
            const float tr7 = wb.w * ct[7] - vb.w * st[7];
            const float ti7 = wb.w * st[7] + vb.w * ct[7];

            const float gh = gvec[hd];
            const float w2 = fc2_w[hd];

            // quad 1: pixels w0 + 128m  (i^ky rotation)
            const float A0 = tr0 + tr4, A2 = tr2 + tr6;
            const float E = A0 + A2, D = A0 - A2;
            const float B13 = (tr1 + tr5) + (tr3 + tr7);
            const float U = (ti1 + ti5) - (ti3 + ti7);
            const float s0 = fmaf(gh, xv[0], E + B13);
            const float s2 = fmaf(gh, xv[2], D - U);
            const float s4 = fmaf(gh, xv[4], E - B13);
            const float s6 = fmaf(gh, xv[6], D + U);
            acc[0] = fmaf(fmaxf(s0, 0.f), w2, acc[0]);
            acc[2] = fmaf(fmaxf(s2, 0.f), w2, acc[2]);
            acc[4] = fmaf(fmaxf(s4, 0.f), w2, acc[4]);
            acc[6] = fmaf(fmaxf(s6, 0.f), w2, acc[6]);

            // quad 2: pixels w0+64+128m  (extra e^{i ky pi/4} rotation)
            const float P = tr0 - tr4, Q = ti6 - ti2;
            const float E2 = P + Q, D2 = P - Q;
            const float B2 = r2c * (((tr1 - ti1) - (tr5 - ti5)) + ((tr7 + ti7) - (tr3 + ti3)));
            const float U2 = r2c * (((tr1 + ti1) - (tr5 + ti5)) - ((tr3 - ti3) + (ti7 - tr7)));
            const float s1p = fmaf(gh, xv[1], E2 + B2);
            const float s3p = fmaf(gh, xv[3], D2 - U2);
            const float s5p = fmaf(gh, xv[5], E2 - B2);
            const float s7p = fmaf(gh, xv[7], D2 + U2);
            acc[1] = fmaf(fmaxf(s1p, 0.f), w2, acc[1]);
            acc[3] = fmaf(fmaxf(s3p, 0.f), w2, acc[3]);
            acc[5] = fmaf(fmaxf(s5p, 0.f), w2, acc[5]);
            acc[7] = fmaf(fmaxf(s7p, 0.f), w2, acc[7]);
        }
        float* op = out + ((size_t)(b * NH + row)) * NW + w0;
        #pragma unroll
        for (int j = 0; j < 8; ++j) op[j * 64] = acc[j];
    }
}

// ---------------------------------------------------------------------------
// k2: fused modes+head. 1024 blocks x 256 threads, ALL co-resident
// (16 KB LDS, 4 blocks/CU of 8-capacity -> spin cannot deadlock).
// Blocks 0..63 produce AH (device-coherent stores) then release-add the
// flag; every block polls the flag (relaxed, L2-bypassing) before phase C.
// Flag was reset by k1 of this replay, so first-run state is always clean.
// ---------------------------------------------------------------------------
__global__ __launch_bounds__(256, 4) void k_mh(
        const float* __restrict__ x, const float* __restrict__ R,
        const float* __restrict__ spec_wr, const float* __restrict__ spec_wi,
        const float* __restrict__ conv_w, const float* __restrict__ conv_b,
        const float* __restrict__ fc0_w, const float* __restrict__ fc0_b,
        const float* __restrict__ fc1_w, const float* __restrict__ fc1_b,
        const float* __restrict__ fc2_w, const float* __restrict__ fc2_b,
        float* __restrict__ AH, float* __restrict__ gvec, float* __restrict__ Kvec,
        int* __restrict__ flag, float* __restrict__ out) {
    __shared__ __align__(16) float sm[4096];
    const int tid = threadIdx.x;

    if (blockIdx.x < 64) {
        phaseB(R, spec_wr, spec_wi, conv_w, conv_b, fc0_w, fc0_b,
               fc1_w, fc1_b, AH, gvec, Kvec, sm, blockIdx.x);
        __syncthreads();            // drains all threads' vmcnt (stores done)
        if (tid == 0)
            __hip_atomic_fetch_add(flag, 1, __ATOMIC_RELEASE, DEV_SCOPE);
    }

    // wait for all 64 producers (one polling lane per block, s_sleep backoff)
    if (tid == 0) {
        while (__hip_atomic_load(flag, __ATOMIC_RELAXED, DEV_SCOPE) < 64)
            __builtin_amdgcn_s_sleep(2);
    }
    __syncthreads();

    phaseC(x, AH, gvec, Kvec, fc2_w, fc2_b, out, sm);
}

// ---------------------------------------------------------------------------
extern "C" void kernel_launch(void* const* d_in, const int* in_sizes, int n_in,
                              void* d_out, int out_size, void* d_ws, size_t ws_size,
                              hipStream_t stream) {
    const float* x       = (const float*)d_in[0];
    const float* fc0_w   = (const float*)d_in[1];
    const float* fc0_b   = (const float*)d_in[2];
    const float* spec_wr = (const float*)d_in[3];
    const float* spec_wi = (const float*)d_in[4];
    const float* conv_w  = (const float*)d_in[5];
    const float* conv_b  = (const float*)d_in[6];
    const float* fc1_w   = (const float*)d_in[7];
    const float* fc1_b   = (const float*)d_in[8];
    const float* fc2_w   = (const float*)d_in[9];
    const float* fc2_b   = (const float*)d_in[10];
    float* outp = (float*)d_out;

    char* ws = (char*)d_ws;
    float* R  = (float*)ws;                       // 8*512*16 floats = 256 KB
    float* AH = (float*)(ws + 262144);            // 8*64*64*2 floats = 256 KB
    float* gv = (float*)(ws + 524288);            // 64 floats
    float* Kv = (float*)(ws + 524288 + 256);      // 64 floats
    int*  flg = (int*)(ws + 524288 + 512);        // producer-done flag

    k_rowdft<<<1024, 256, 0, stream>>>(x, R, flg);
    k_mh<<<1024, 256, 0, stream>>>(x, R, spec_wr, spec_wi, conv_w, conv_b,
                                   fc0_w, fc0_b, fc1_w, fc1_b, fc2_w, fc2_b,
                                   AH, gv, Kv, flg, outp);
}

// Round 4
// 143.829 us; speedup vs baseline: 2.0946x; 1.0420x over previous
//
#include <hip/hip_runtime.h>
#include <math.h>

#define NB 8
#define NH 512
#define NW 512
#define ANG512 0.01227184630308513f
#define SPEC_D 16384   // per-depth stride of spec_wr/spec_wi (16*16*8*8)

#define DEV_SCOPE __HIP_MEMORY_SCOPE_AGENT

// ---------------------------------------------------------------------------
// k_pre: 512 blocks, 8 rows/block (2 rows per wave).
// Per wave: 8-mode row DFT of x[b,0,row,:] via the parity trick, butterfly
// reduce, deposit to LDS.  Then 128 threads rotate each row's spectrum by
// e^{-2pi i kx row/512} and sum over the block's 8 rows -> one 128-float
// partial P[b][rg][kx][q].  The former 512-row col-DFT in phaseB becomes a
// 64-partial sum.  Block 0 also resets the 8 per-batch handoff flags
// (visible to k2 via the dispatch boundary).
// ---------------------------------------------------------------------------
__global__ __launch_bounds__(256) void k_pre(const float* __restrict__ x,
                                             float* __restrict__ P,
                                             int* __restrict__ flags) {
    __shared__ float wred[8][16];
    const int tid = threadIdx.x;
    const int w = tid >> 6, lane = tid & 63;
    const int gid = blockIdx.x;            // 0..511
    const int b = gid >> 6, rg = gid & 63;

    if (gid == 0 && tid < 8)
        __hip_atomic_store(&flags[tid * 32], 0, __ATOMIC_RELAXED, DEV_SCOPE);

    #pragma unroll
    for (int rr = 0; rr < 2; ++rr) {
        const int row = rg * 8 + w + 4 * rr;
        const float* xr = x + ((size_t)(b * NH + row)) * NW;

        float p[16];
        #pragma unroll
        for (int j = 0; j < 16; ++j) p[j] = 0.f;

        #pragma unroll
        for (int j = 0; j < 4; ++j) {
            const int ww = lane + (j << 6);
            const float xa = xr[ww], xb = xr[ww + 256];
            const float a = xa + xb, d = xa - xb;   // tw(w+256)=(-1)^k tw(w)
            float c1, s1;
            __sincosf(ANG512 * (float)ww, &s1, &c1);
            p[0] += a;
            p[1] = fmaf(d, c1, p[1]);
            p[9] = fmaf(-d, s1, p[9]);
            const float c2k = 2.f * c1;
            float ckm = 1.f, skm = 0.f, ck = c1, sk = s1;
            #pragma unroll
            for (int k = 2; k < 8; ++k) {
                const float cn = fmaf(c2k, ck, -ckm);
                const float sn = fmaf(c2k, sk, -skm);
                ckm = ck; skm = sk; ck = cn; sk = sn;
                const float v = (k & 1) ? d : a;
                p[k]     = fmaf(v, ck, p[k]);
                p[8 + k] = fmaf(-v, sk, p[8 + k]);
            }
        }
        // wave butterfly reduce (all lanes end with the totals)
        #pragma unroll
        for (int m = 1; m < 64; m <<= 1) {
            #pragma unroll
            for (int j = 0; j < 16; ++j) p[j] += __shfl_xor(p[j], m);
        }
        if (lane < 16) wred[w + 4 * rr][lane] = p[lane];
    }
    __syncthreads();

    // rotate + sum over the block's 8 rows -> partial for (b,rg,kx,q)
    if (tid < 128) {
        const int kx = tid >> 4, q = tid & 15, qm = q & 7;
        float acc = 0.f;
        #pragma unroll
        for (int r = 0; r < 8; ++r) {
            const int row = rg * 8 + r;
            const int m = (kx * row) & 511;
            float cm, s2;
            __sincosf(ANG512 * (float)m, &s2, &cm);   // e^{-i th m} = (cm,-sm)
            const float rre = wred[r][qm], rim = wred[r][8 + qm];
            acc += (q < 8) ? (rre * cm + rim * s2)
                           : (rim * cm - rre * s2);
        }
        P[((size_t)((b * 64 + rg) * 8 + kx)) * 16 + q] = acc;
    }
}

// ---------------------------------------------------------------------------
// Phase C (device fn): head. 4 rows/block (wave = row), 8 px/thread.
// sm: 4096 floats; WHr = sm[0..2047] as [4][512], WHi = sm[2048..4095].
// ---------------------------------------------------------------------------
__device__ __forceinline__ void phaseC(
        const float* __restrict__ x, const float* __restrict__ AH,
        const float* __restrict__ gvec, const float* __restrict__ Kvec,
        const float* __restrict__ fc2_w, const float* __restrict__ fc2_b,
        float* __restrict__ out, float* sm) {
    float* WHr = sm;
    float* WHi = sm + 2048;

    const int tid = threadIdx.x;
    const int b = blockIdx.x >> 7;       // 1024 blocks total
    const int rp = blockIdx.x & 127;     // group of 4 rows
    const int rl = tid >> 6;             // wave index = local row
    const int row = rp * 4 + rl;
    const int w0 = tid & 63;

    const float* xp = x + ((size_t)(b * NH + row)) * NW + w0;
    float xv[8];
    #pragma unroll
    for (int j = 0; j < 8; ++j) xv[j] = xp[j * 64];

    // ---- WH build: 8 entries/thread for this wave's row ----
    {
        float c1, s1;
        __sincosf(ANG512 * (float)row, &s1, &c1);
        float ctr[8], str[8];
        ctr[0] = 1.f; str[0] = 0.f; ctr[1] = c1; str[1] = s1;
        const float c2k = 2.f * c1;
        #pragma unroll
        for (int k = 2; k < 8; ++k) {
            ctr[k] = fmaf(c2k, ctr[k - 1], -ctr[k - 2]);
            str[k] = fmaf(c2k, str[k - 1], -str[k - 2]);
        }
        #pragma unroll
        for (int j = 0; j < 8; ++j) {
            const int idx = w0 + j * 64;     // hd*8 + ky
            const int hd = idx >> 3, ky = idx & 7;
            const float4* ap = (const float4*)(AH + ((size_t)(b * 64 + hd) * 8 + ky) * 16);
            const float4 a0 = ap[0], a1 = ap[1], a2 = ap[2], a3 = ap[3];
            float wr = a0.x, wi = a0.y;      // kx=0
            wr = fmaf(a0.z, ctr[1], wr); wr = fmaf(-a0.w, str[1], wr);
            wi = fmaf(a0.z, str[1], wi); wi = fmaf(a0.w, ctr[1], wi);
            wr = fmaf(a1.x, ctr[2], wr); wr = fmaf(-a1.y, str[2], wr);
            wi = fmaf(a1.x, str[2], wi); wi = fmaf(a1.y, ctr[2], wi);
            wr = fmaf(a1.z, ctr[3], wr); wr = fmaf(-a1.w, str[3], wr);
            wi = fmaf(a1.z, str[3], wi); wi = fmaf(a1.w, ctr[3], wi);
            wr = fmaf(a2.x, ctr[4], wr); wr = fmaf(-a2.y, str[4], wr);
            wi = fmaf(a2.x, str[4], wi); wi = fmaf(a2.y, ctr[4], wi);
            wr = fmaf(a2.z, ctr[5], wr); wr = fmaf(-a2.w, str[5], wr);
            wi = fmaf(a2.z, str[5], wi); wi = fmaf(a2.w, ctr[5], wi);
            wr = fmaf(a3.x, ctr[6], wr); wr = fmaf(-a3.y, str[6], wr);
            wi = fmaf(a3.x, str[6], wi); wi = fmaf(a3.y, ctr[6], wi);
            wr = fmaf(a3.z, ctr[7], wr); wr = fmaf(-a3.w, str[7], wr);
            wi = fmaf(a3.z, str[7], wi); wi = fmaf(a3.w, ctr[7], wi);
            if (ky == 0) wr += Kvec[hd];
            WHr[rl * 512 + idx] = wr;
            WHi[rl * 512 + idx] = wi;
        }
    }
    __syncthreads();

    // ---- 8 px/thread: w0 + 64*j ----
    {
        float c1, s1;
        __sincosf(ANG512 * (float)w0, &s1, &c1);
        float ct[8], st[8];
        ct[0] = 1.f; st[0] = 0.f; ct[1] = c1; st[1] = s1;
        const float c2k = 2.f * c1;
        #pragma unroll
        for (int k = 2; k < 8; ++k) {
            ct[k] = fmaf(c2k, ct[k - 1], -ct[k - 2]);
            st[k] = fmaf(c2k, st[k - 1], -st[k - 2]);
        }
        const float r2c = 0.70710678118654752f;
        const float* WR = WHr + rl * 512;
        const float* WI = WHi + rl * 512;
        const float fc2b = fc2_b[0];
        float acc[8];
        #pragma unroll
        for (int j = 0; j < 8; ++j) acc[j] = fc2b;

        #pragma unroll 4
        for (int hd = 0; hd < 64; ++hd) {
            const float4* r4 = (const float4*)(WR + hd * 8);
            const float4 wa = r4[0], wb = r4[1];
            const float4* i4 = (const float4*)(WI + hd * 8);
            const float4 va = i4[0], vb = i4[1];
            const float tr0 = wa.x;
            const float tr1 = wa.y * ct[1] - va.y * st[1];
            const float ti1 = wa.y * st[1] + va.y * ct[1];
            const float tr2 = wa.z * ct[2] - va.z * st[2];
            const float ti2 = wa.z * st[2] + va.z * ct[2];
            const float tr3 = wa.w * ct[3] - va.w * st[3];
            const float ti3 = wa.w * st[3] + va.w * ct[3];
            const float tr4 = wb.x * ct[4] - vb.x * st[4];
            const float tr5 = wb.y * ct[5] - vb.y * st[5];
            const float ti5 = wb.y * st[5] + vb.y * ct[5];
            const float tr6 = wb.z * ct[6] - vb.z * st[6];
            const float ti6 = wb.z * st[6] + vb.z * ct[6];
            const float tr7 = wb.w * ct[7] - vb.w * st[7];
            const float ti7 = wb.w * st[7] + vb.w * ct[7];

            const float gh = gvec[hd];
            const float w2 = fc2_w[hd];

            // quad 1: pixels w0 + 128m  (i^ky rotation)
            const float A0 = tr0 + tr4, A2 = tr2 + tr6;
            const float E = A0 + A2, D = A0 - A2;
            const float B13 = (tr1 + tr5) + (tr3 + tr7);
            const float U = (ti1 + ti5) - (ti3 + ti7);
            const float s0 = fmaf(gh, xv[0], E + B13);
            const float s2 = fmaf(gh, xv[2], D - U);
            const float s4 = fmaf(gh, xv[4], E - B13);
            const float s6 = fmaf(gh, xv[6], D + U);
            acc[0] = fmaf(fmaxf(s0, 0.f), w2, acc[0]);
            acc[2] = fmaf(fmaxf(s2, 0.f), w2, acc[2]);
            acc[4] = fmaf(fmaxf(s4, 0.f), w2, acc[4]);
            acc[6] = fmaf(fmaxf(s6, 0.f), w2, acc[6]);

            // quad 2: pixels w0+64+128m  (extra e^{i ky pi/4} rotation)
            const float P = tr0 - tr4, Q = ti6 - ti2;
            const float E2 = P + Q, D2 = P - Q;
            const float B2 = r2c * (((tr1 - ti1) - (tr5 - ti5)) + ((tr7 + ti7) - (tr3 + ti3)));
            const float U2 = r2c * (((tr1 + ti1) - (tr5 + ti5)) - ((tr3 - ti3) + (ti7 - tr7)));
            const float s1p = fmaf(gh, xv[1], E2 + B2);
            const float s3p = fmaf(gh, xv[3], D2 - U2);
            const float s5p = fmaf(gh, xv[5], E2 - B2);
            const float s7p = fmaf(gh, xv[7], D2 + U2);
            acc[1] = fmaf(fmaxf(s1p, 0.f), w2, acc[1]);
            acc[3] = fmaf(fmaxf(s3p, 0.f), w2, acc[3]);
            acc[5] = fmaf(fmaxf(s5p, 0.f), w2, acc[5]);
            acc[7] = fmaf(fmaxf(s7p, 0.f), w2, acc[7]);
        }
        float* op = out + ((size_t)(b * NH + row)) * NW + w0;
        #pragma unroll
        for (int j = 0; j < 8; ++j) op[j * 64] = acc[j];
    }
}

// ---------------------------------------------------------------------------
// k_mh: fused modes+head. 1024 blocks x 256 threads, all co-resident
// (16 KB LDS, 4 blocks/CU). Blocks 0..63 (b=bid>>3, kx=bid&7): sum 64
// partials -> X2; recurrence; AH fold (device-scope stores); kx==0 blocks
// also produce per-batch gvec/Kvec copies; then release-add flags[b].
// All blocks spin on THEIR batch's flag line (8 distinct cachelines,
// ~120 pollers each, s_sleep backoff) before phase C.
// ---------------------------------------------------------------------------
__global__ __launch_bounds__(256, 4) void k_mh(
        const float* __restrict__ x, const float* __restrict__ P,
        const float* __restrict__ spec_wr, const float* __restrict__ spec_wi,
        const float* __restrict__ conv_w, const float* __restrict__ conv_b,
        const float* __restrict__ fc0_w, const float* __restrict__ fc0_b,
        const float* __restrict__ fc1_w, const float* __restrict__ fc1_b,
        const float* __restrict__ fc2_w, const float* __restrict__ fc2_b,
        float* __restrict__ AH, float* __restrict__ gv, float* __restrict__ Kv,
        int* __restrict__ flags, float* __restrict__ out) {
    __shared__ __align__(16) float sm[4096];
    const int tid = threadIdx.x;
    const int bid = blockIdx.x;

    if (bid < 64) {
        // sm layout for the producer phase:
        float* red2  = sm;            // 256
        float* X2    = sm + 256;      // 16
        float* Xr    = sm + 272;      // 128
        float* Xi    = sm + 400;      // 128
        float* Fr    = sm + 528;      // 128
        float* Fi    = sm + 656;      // 128
        float* Ar    = sm + 784;      // 128
        float* Ai    = sm + 912;      // 128
        float* Pm    = sm + 1040;     // 512 [2][256]
        float* fc1_s = sm + 1552;     // 1024
        float* ps    = sm + 2576;     // 64

        const int b = bid >> 3;
        const int kx = bid & 7;

        // ---- Pm[0] = C2*C1, Pm[1] = C2, stage fc1 ----
        {
            const int o = tid >> 4, c = tid & 15;
            float s = 0.f;
            for (int k = 0; k < 16; ++k)
                s += conv_w[512 + o * 16 + k] * conv_w[256 + k * 16 + c];
            Pm[tid] = s;
        }
        Pm[256 + tid] = conv_w[512 + tid];
        #pragma unroll
        for (int k = 0; k < 4; ++k) fc1_s[tid + k * 256] = fc1_w[tid + k * 256];

        // ---- X2 = sum of 64 partials (former col-DFT, now trivial) ----
        {
            const int q = tid & 15, c = tid >> 4;
            float acc = 0.f;
            #pragma unroll
            for (int m = 0; m < 4; ++m) {
                const int rg = c + 16 * m;
                acc += P[((size_t)((b * 64 + rg) * 8 + kx)) * 16 + q];
            }
            red2[c * 16 + q] = acc;
        }
        __syncthreads();
        if (tid < 16) {
            float s = 0.f;
            #pragma unroll
            for (int c = 0; c < 16; ++c) s += red2[c * 16 + tid];
            X2[tid] = s;
        }
        __syncthreads();

        // ---- recurrence: thread = (o,ky), tid < 128 ----
        const bool act = (tid < 128);
        const int o = tid >> 3, ky = tid & 7;
        if (act) {
            const float inv = 1.f / (512.f * 512.f);
            float xr0 = fc0_w[o] * X2[ky] * inv;
            float xi0 = fc0_w[o] * X2[8 + ky] * inv;
            if (kx == 0 && ky == 0) xr0 += fc0_b[o];
            Xr[o * 8 + ky] = xr0; Xi[o * 8 + ky] = xi0;
            Ar[o * 8 + ky] = 0.f; Ai[o * 8 + ky] = 0.f;
        }
        __syncthreads();

        for (int dd = 0; dd < 3; ++dd) {
            if (act) {
                float fr = 0.f, fi = 0.f;
                const float* wrp = spec_wr + (size_t)dd * SPEC_D + o * 64 + kx * 8 + ky;
                const float* wip = spec_wi + (size_t)dd * SPEC_D + o * 64 + kx * 8 + ky;
                #pragma unroll
                for (int i = 0; i < 16; ++i) {
                    const float wre = wrp[i * 1024];
                    const float wim = wip[i * 1024];
                    const float xr0 = Xr[i * 8 + ky], xi0 = Xi[i * 8 + ky];
                    fr += xr0 * wre - xi0 * wim;
                    fi += xr0 * wim + xi0 * wre;
                }
                Fr[o * 8 + ky] = fr; Fi[o * 8 + ky] = fi;
            }
            __syncthreads();
            float xnr = 0.f, xni = 0.f;
            if (act) {
                float ar, ai;
                if (dd == 2) {
                    ar = Fr[o * 8 + ky]; ai = Fi[o * 8 + ky];
                } else {
                    ar = 0.f; ai = 0.f;
                    #pragma unroll
                    for (int c = 0; c < 16; ++c) {
                        const float pv = Pm[dd * 256 + o * 16 + c];
                        ar = fmaf(pv, Fr[c * 8 + ky], ar);
                        ai = fmaf(pv, Fi[c * 8 + ky], ai);
                    }
                }
                Ar[o * 8 + ky] += ar; Ai[o * 8 + ky] += ai;
                if (dd < 2) {
                    const float fr0 = Fr[o * 8 + ky], fi0 = Fi[o * 8 + ky];
                    if (ky == 0) {
                        if (kx == 0) { xnr = fr0; xni = 0.f; }
                        else         { xnr = 0.5f * fr0; xni = 0.5f * fi0; }
                    } else { xnr = fr0; xni = fi0; }
                    #pragma unroll
                    for (int c = 0; c < 16; ++c) {
                        const float cc = conv_w[dd * 256 + o * 16 + c];
                        xnr = fmaf(cc, Xr[c * 8 + ky], xnr);
                        xni = fmaf(cc, Xi[c * 8 + ky], xni);
                    }
                    if (kx == 0 && ky == 0) xnr += conv_b[dd * 16 + o];
                }
            }
            __syncthreads();
            if (act && dd < 2) { Xr[o * 8 + ky] = xnr; Xi[o * 8 + ky] = xni; }
            __syncthreads();
        }

        // ---- fold fc1 -> AH[b,hd,ky,kx], device-coherent stores ----
        #pragma unroll
        for (int k2 = 0; k2 < 2; ++k2) {
            const int idx = tid + k2 * 256;      // hd*8 + ky2
            const int hd = idx >> 3, ky2 = idx & 7;
            float ar = 0.f, ai = 0.f;
            #pragma unroll
            for (int c = 0; c < 16; ++c) {
                const float f = fc1_s[c * 64 + hd];
                ar = fmaf(f, Ar[c * 8 + ky2], ar);
                ai = fmaf(f, Ai[c * 8 + ky2], ai);
            }
            const float ck = (ky2 == 0) ? 1.f : 2.f;    // Hermitian doubling
            const size_t off = ((((size_t)(b * 64 + hd)) * 8 + ky2) * 8 + kx) * 2;
            __hip_atomic_store(&AH[off],     ck * ar, __ATOMIC_RELAXED, DEV_SCOPE);
            __hip_atomic_store(&AH[off + 1], ck * ai, __ATOMIC_RELAXED, DEV_SCOPE);
        }

        // ---- kx==0 blocks: per-batch gvec/Kvec copy (weight-only math) ----
        if (kx == 0) {
            if (tid < 16) {
                float su = 0.f, sb = 0.f;
                for (int c = 0; c < 16; ++c) {
                    su += conv_w[tid * 16 + c] * fc0_w[c];
                    sb += conv_w[tid * 16 + c] * fc0_b[c];
                }
                ps[tid] = su; ps[16 + tid] = sb;
            }
            __syncthreads();
            if (tid < 16) {
                float dv = 0.f, ev = conv_b[32 + tid];
                for (int k = 0; k < 16; ++k) {
                    dv += Pm[tid * 16 + k] * ps[k];
                    ev += Pm[tid * 16 + k] * (ps[16 + k] + conv_b[k]);
                    ev += conv_w[512 + tid * 16 + k] * conv_b[16 + k];
                }
                ps[32 + tid] = dv; ps[48 + tid] = ev;
            }
            __syncthreads();
            if (tid < 64) {
                float g = 0.f, K = fc1_b[tid];
                for (int c = 0; c < 16; ++c) {
                    g = fmaf(fc1_w[c * 64 + tid], ps[32 + c], g);
                    K = fmaf(fc1_w[c * 64 + tid], ps[48 + c], K);
                }
                __hip_atomic_store(&gv[b * 64 + tid], g, __ATOMIC_RELAXED, DEV_SCOPE);
                __hip_atomic_store(&Kv[b * 64 + tid], K, __ATOMIC_RELAXED, DEV_SCOPE);
            }
        }
        __syncthreads();            // all producer stores issued
        if (tid == 0)
            __hip_atomic_fetch_add(&flags[b * 32], 1, __ATOMIC_RELEASE, DEV_SCOPE);
    }

    // ---- wait for this batch's 8 producers (distributed flag lines) ----
    const int cb = bid >> 7;
    if (tid == 0) {
        while (__hip_atomic_load(&flags[cb * 32], __ATOMIC_RELAXED, DEV_SCOPE) < 8)
            __builtin_amdgcn_s_sleep(8);
    }
    __syncthreads();

    phaseC(x, AH, gv + cb * 64, Kv + cb * 64, fc2_w, fc2_b, out, sm);
}

// ---------------------------------------------------------------------------
extern "C" void kernel_launch(void* const* d_in, const int* in_sizes, int n_in,
                              void* d_out, int out_size, void* d_ws, size_t ws_size,
                              hipStream_t stream) {
    const float* x       = (const float*)d_in[0];
    const float* fc0_w   = (const float*)d_in[1];
    const float* fc0_b   = (const float*)d_in[2];
    const float* spec_wr = (const float*)d_in[3];
    const float* spec_wi = (const float*)d_in[4];
    const float* conv_w  = (const float*)d_in[5];
    const float* conv_b  = (const float*)d_in[6];
    const float* fc1_w   = (const float*)d_in[7];
    const float* fc1_b   = (const float*)d_in[8];
    const float* fc2_w   = (const float*)d_in[9];
    const float* fc2_b   = (const float*)d_in[10];
    float* outp = (float*)d_out;

    char* ws = (char*)d_ws;
    float* P   = (float*)ws;                       // 8*64*8*16 floats = 256 KB
    float* AH  = (float*)(ws + 262144);            // 8*64*64*2 floats = 256 KB
    float* gv  = (float*)(ws + 524288);            // 8*64 floats = 2 KB
    float* Kv  = (float*)(ws + 526336);            // 8*64 floats = 2 KB
    int*  flg  = (int*)(ws + 528384);              // 8 flags on distinct lines

    k_pre<<<512, 256, 0, stream>>>(x, P, flg);
    k_mh<<<1024, 256, 0, stream>>>(x, P, spec_wr, spec_wi, conv_w, conv_b,
                                   fc0_w, fc0_b, fc1_w, fc1_b, fc2_w, fc2_b,
                                   AH, gv, Kv, flg, outp);
}